// Round 6
// baseline (137.337 us; speedup 1.0000x reference)
//
#include <hip/hip_runtime.h>
#include <stdint.h>

#define N_REAL 500
#define NPAD   512
#define K_IN   3072
#define NBATCH 8192
#define NOUT   10
#define RADIUS 20.0f
#define VOLF   100.0f

typedef __attribute__((ext_vector_type(8))) __bf16 bf16x8;
typedef __attribute__((ext_vector_type(4))) float  f32x4;
typedef __attribute__((ext_vector_type(4))) unsigned short us4;

__device__ __forceinline__ unsigned short f2bf(float f) {
    unsigned int u = __float_as_uint(f);
    u += 0x7FFFu + ((u >> 16) & 1u);           // round-to-nearest-even
    return (unsigned short)(u >> 16);
}
__device__ __forceinline__ float bf2f(unsigned short h) {
    return __uint_as_float(((unsigned int)h) << 16);
}
// HW packed f32->bf16 (RNE), 2 insts per float4
__device__ __forceinline__ uint2 cvt_pk4(float4 v) {
    uint2 r;
    asm("v_cvt_pk_bf16_f32 %0, %1, %2" : "=v"(r.x) : "v"(v.x), "v"(v.y));
    asm("v_cvt_pk_bf16_f32 %0, %1, %2" : "=v"(r.y) : "v"(v.z), "v"(v.w));
    return r;
}

#define GLOBAL_AS __attribute__((address_space(1)))
#define LDS_AS    __attribute__((address_space(3)))
__device__ __forceinline__ void glds16(const void* g, void* l) {
    __builtin_amdgcn_global_load_lds((const GLOBAL_AS void*)g, (LDS_AS void*)l, 16, 0, 0);
}

// ---------------- prep1 ----------------
__global__ void prep1(const float* __restrict__ positions,
                      const float* __restrict__ features,
                      const float* __restrict__ out_w,
                      const float* __restrict__ biases,
                      float* __restrict__ feat_norm,   // [512][64]
                      float* __restrict__ pos_c,       // [512][4]
                      float* __restrict__ inw,         // [512]
                      float* __restrict__ biasp,       // [512]
                      float* __restrict__ wout)        // [512][10]
{
    int n = threadIdx.x;  // 512 threads, 1 block
    float e_in = 0.f, e_out = 0.f;
    float px = 0.f, py = 0.f, pz = 0.f;
    if (n < N_REAL) {
        px = fminf(fmaxf(positions[n*3+0], 0.1f), VOLF - 0.1f);
        py = fminf(fmaxf(positions[n*3+1], 0.1f), VOLF - 0.1f);
        pz = fminf(fmaxf(positions[n*3+2], 0.1f), VOLF - 0.1f);
        float xn = px / VOLF;
        e_in  = expf(-2.f * xn);
        e_out = expf(2.f * (xn - 1.f));
        float ss = 0.f;
        for (int f = 0; f < 64; ++f) { float v = features[n*64+f]; ss += v*v; }
        float nm = fmaxf(sqrtf(ss), 1e-6f);
        for (int f = 0; f < 64; ++f) feat_norm[n*64+f] = features[n*64+f] / nm;
    } else {
        for (int f = 0; f < 64; ++f) feat_norm[n*64+f] = 0.f;
    }
    pos_c[n*4+0] = px; pos_c[n*4+1] = py; pos_c[n*4+2] = pz; pos_c[n*4+3] = 0.f;

    __shared__ float s_in[512], s_out[512];
    s_in[n] = e_in; s_out[n] = e_out;
    __syncthreads();
    for (int s = 256; s > 0; s >>= 1) {
        if (n < s) { s_in[n] += s_in[n+s]; s_out[n] += s_out[n+s]; }
        __syncthreads();
    }
    float sum_in  = s_in[0]  + 1e-6f;
    float sum_out = s_out[0] + 1e-6f;

    inw[n]   = (n < N_REAL) ? (e_in / sum_in) : 0.f;
    biasp[n] = (n < N_REAL) ? biases[n] : 0.f;
    float wo = (n < N_REAL) ? (e_out / sum_out) : 0.f;
    for (int o = 0; o < NOUT; ++o)
        wout[n*NOUT + o] = (n < N_REAL) ? out_w[n*NOUT + o] * wo : 0.f;
}

// ---------------- prep2 ----------------
__global__ void prep2(const float* __restrict__ pos_c,
                      const float* __restrict__ feat_norm,
                      unsigned short* __restrict__ conn_w)   // [512][512] bf16
{
    int i = blockIdx.x;   // 512
    int t = threadIdx.x;  // 128
    __shared__ float fi[64];
    __shared__ float spos[4];
    __shared__ float red[128];
    if (t < 64) fi[t] = feat_norm[i*64 + t];
    if (t < 4)  spos[t] = pos_c[i*4 + t];
    __syncthreads();

    float w[4];
    float part = 0.f;
    for (int jj = 0; jj < 4; ++jj) {
        int j = t + jj*128;
        float val = 0.f;
        if (i < N_REAL && j < N_REAL) {
            float dx = spos[0] - pos_c[j*4+0];
            float dy = spos[1] - pos_c[j*4+1];
            float dz = spos[2] - pos_c[j*4+2];
            float sq = dx*dx + dy*dy + dz*dz;
            if (sq > 0.f) {
                float dist = sqrtf(sq);
                if (dist < RADIUS) {
                    float att = expf(-dist / RADIUS);
                    float sim = 0.f;
                    const float4* fj = (const float4*)(feat_norm + j*64);
                    const float4* fi4 = (const float4*)fi;
                    #pragma unroll
                    for (int f = 0; f < 16; ++f) {
                        float4 a = fi4[f]; float4 b = fj[f];
                        sim += a.x*b.x + a.y*b.y + a.z*b.z + a.w*b.w;
                    }
                    sim = fminf(fmaxf(sim, -1.f), 1.f);
                    val = att * (0.5f + 0.5f*sim);
                }
            }
        }
        w[jj] = val; part += val;
    }
    red[t] = part;
    __syncthreads();
    for (int s = 64; s > 0; s >>= 1) {
        if (t < s) red[t] += red[t+s];
        __syncthreads();
    }
    float inv = 1.f / (red[0] + 1e-6f);
    for (int jj = 0; jj < 4; ++jj)
        conn_w[(long)i*NPAD + t + jj*128] = f2bf(w[jj] * inv);
}

// ---------------- cast/pad f32 -> bf16 ----------------
__global__ void cast_pad(const float* __restrict__ src, unsigned short* __restrict__ dst,
                         long total_q, long src_q)
{
    long i = (long)blockIdx.x * blockDim.x + threadIdx.x;
    long stride = (long)gridDim.x * blockDim.x;
    for (; i < total_q; i += stride) {
        us4 o;
        if (i < src_q) {
            float4 v = ((const float4*)src)[i];
            o[0] = f2bf(v.x); o[1] = f2bf(v.y); o[2] = f2bf(v.z); o[3] = f2bf(v.w);
        } else {
            o[0] = 0; o[1] = 0; o[2] = 0; o[3] = 0;
        }
        ((us4*)dst)[i] = o;
    }
}

// Block map for 256 blocks = 128 m-panels x 2 n-halves.
// Each XCD owns 16 consecutive m-panels; the two n-halves of an m-panel are
// adjacent on the same XCD so the second X read hits that XCD's L2.
__device__ __forceinline__ void block_map(int b, int& m0, int& n0) {
    int xcd = b & 7, loc = b >> 3;          // loc 0..31
    m0 = (xcd*16 + (loc >> 1)) * 64;
    n0 = (loc & 1) * 256;
}

// ============ unified GEMM: BM=64, BN=256, BK=64, 512 thr (8 waves 2m x 4n) ============
// MODE 0: A = X (f32, fused cast), C = acc*inw[n]+biasp[n]
// MODE 1: A = act (bf16),          C = min(relu(actOld + 0.5*acc), 50)
template<int MODE>
__global__ __launch_bounds__(512)
void gemm_main(const float* __restrict__ Xf,           // MODE0: [8192][3072] f32
               const unsigned short* __restrict__ Abf, // MODE1: [8192][512] bf16
               const unsigned short* __restrict__ B,   // [512][K] bf16
               unsigned short* __restrict__ Cbf,       // [8192][512] bf16
               const unsigned short* __restrict__ actOld,
               const float* __restrict__ inw,
               const float* __restrict__ biasp,
               int K)
{
    __shared__ unsigned short As[2][64*64];   // 2 x  8 KiB, swizzled
    __shared__ unsigned short Bs[2][256*64];  // 2 x 32 KiB, swizzled

    const int tid  = threadIdx.x;
    const int lane = tid & 63;
    const int wave = tid >> 6;
    int m0, n0; block_map(blockIdx.x, m0, n0);
    const int wm = (wave >> 2) * 32;          // 2 m-waves
    const int wn = (wave & 3) * 64;           // 4 n-waves

    f32x4 acc[2][4];
    #pragma unroll
    for (int i = 0; i < 2; ++i)
        #pragma unroll
        for (int j = 0; j < 4; ++j)
            acc[i][j] = (f32x4){0.f,0.f,0.f,0.f};

    // ---- staging descriptors ----
    // B: 256 rows x 64k bf16 = 32 KB = 2048x16B; 512 thr -> 4 glds16/thread
    const char* gB[4]; int lBo[4];
    #pragma unroll
    for (int s = 0; s < 4; ++s) {
        int o = tid*16 + s*8192;
        int row = o >> 7, d = o & 127;
        gB[s] = (const char*)B + (long)(n0 + row) * (K*2) + (d ^ ((row & 7) << 4));
        lBo[s] = o;
    }
    // A MODE0: 64 rows x 16 float4 = 1024 f4; 2/thread (reg-stage + cvt)
    const float4* gA[2]; int lAo[2];
    // A MODE1: 64 rows x 128B = 8 KB = 512x16B; 1 glds16/thread
    const char* gA1 = nullptr; int lAo1 = 0;
    if (MODE == 0) {
        #pragma unroll
        for (int s = 0; s < 2; ++s) {
            int f = tid + s*512;
            int row = f >> 4, c4 = f & 15;
            gA[s] = (const float4*)(Xf + (long)(m0 + row) * K) + c4;
            lAo[s] = row*128 + ((c4*8) ^ ((row & 7) << 4));
        }
    } else {
        int o = tid*16;
        int row = o >> 7, d = o & 127;
        gA1 = (const char*)Abf + (long)(m0 + row) * (K*2) + (d ^ ((row & 7) << 4));
        lAo1 = o;
    }

    const int NT = K >> 6;   // 48 or 8

    // ---- prologue: tile 0 -> buf 0 ----
    float4 v[2];
    if (MODE == 0) {
        #pragma unroll
        for (int s = 0; s < 2; ++s) { v[s] = gA[s][0]; gA[s] += 16; }
        __builtin_amdgcn_sched_barrier(0);
    } else {
        glds16(gA1, (char*)As[0] + lAo1); gA1 += 128;
    }
    #pragma unroll
    for (int s = 0; s < 4; ++s) { glds16(gB[s], (char*)Bs[0] + lBo[s]); gB[s] += 128; }
    if (MODE == 0) {
        #pragma unroll
        for (int s = 0; s < 2; ++s)
            *(uint2*)((char*)As[0] + lAo[s]) = cvt_pk4(v[s]);
        asm volatile("s_waitcnt lgkmcnt(0)" ::: "memory");
    }

    for (int t = 0; t < NT; ++t) {
        const int cur = t & 1;
        const bool more = (t < NT-1);
        if (more) {
            if (MODE == 0) {
                #pragma unroll
                for (int s = 0; s < 2; ++s) { v[s] = gA[s][0]; gA[s] += 16; }
                __builtin_amdgcn_sched_barrier(0);
                #pragma unroll
                for (int s = 0; s < 4; ++s) { glds16(gB[s], (char*)Bs[cur^1] + lBo[s]); gB[s] += 128; }
                // queue: [B(t):4, A(t+1):2, B(t+1):4] -> vmcnt(6) drains B(t) only
                asm volatile("s_waitcnt vmcnt(6)" ::: "memory");
            } else {
                glds16(gA1, (char*)As[cur^1] + lAo1); gA1 += 128;
                #pragma unroll
                for (int s = 0; s < 4; ++s) { glds16(gB[s], (char*)Bs[cur^1] + lBo[s]); gB[s] += 128; }
                // queue: [t:5, t+1:5] -> vmcnt(5) drains tile t only
                asm volatile("s_waitcnt vmcnt(5)" ::: "memory");
            }
        } else {
            asm volatile("s_waitcnt vmcnt(0)" ::: "memory");
        }
        __builtin_amdgcn_s_barrier();   // tile t fully in LDS for all waves

        #pragma unroll
        for (int kk = 0; kk < 2; ++kk) {
            const int cb = kk*64 + (lane >> 4) * 16;
            bf16x8 afr[2], bfr[4];
            #pragma unroll
            for (int i = 0; i < 2; ++i) {
                int r = wm + i*16 + (lane & 15);
                afr[i] = *(const bf16x8*)((const char*)As[cur] + r*128 + (cb ^ ((r & 7) << 4)));
            }
            #pragma unroll
            for (int j = 0; j < 4; ++j) {
                int r = wn + j*16 + (lane & 15);
                bfr[j] = *(const bf16x8*)((const char*)Bs[cur] + r*128 + (cb ^ ((r & 7) << 4)));
            }
            #pragma unroll
            for (int i = 0; i < 2; ++i)
                #pragma unroll
                for (int j = 0; j < 4; ++j)
                    acc[i][j] = __builtin_amdgcn_mfma_f32_16x16x32_bf16(afr[i], bfr[j], acc[i][j], 0, 0, 0);
        }

        if (more) {
            if (MODE == 0) {
                // write A(t+1): compiler waits the 2 f4 loads, leaves B(t+1) in flight
                #pragma unroll
                for (int s = 0; s < 2; ++s)
                    *(uint2*)((char*)As[cur^1] + lAo[s]) = cvt_pk4(v[s]);
                asm volatile("s_waitcnt lgkmcnt(0)" ::: "memory");
            }
            __builtin_amdgcn_s_barrier();  // buf cur reads done before overwrite
        }
    }

    // ---- epilogue ----
    const int mbase = m0 + wm + (lane >> 4) * 4;
    const int nbase = n0 + wn + (lane & 15);
    #pragma unroll
    for (int j = 0; j < 4; ++j) {
        const int n = nbase + j*16;
        float win = 0.f, bia = 0.f;
        if (MODE == 0) { win = inw[n]; bia = biasp[n]; }
        #pragma unroll
        for (int i = 0; i < 2; ++i)
            #pragma unroll
            for (int r = 0; r < 4; ++r) {
                const long m = mbase + i*16 + r;
                float vv;
                if (MODE == 0) {
                    vv = acc[i][j][r] * win + bia;
                } else {
                    float old = bf2f(actOld[m*NPAD + n]);
                    vv = fminf(fmaxf(old + 0.5f * acc[i][j][r], 0.f), 50.f);
                }
                Cbf[m*NPAD + n] = f2bf(vv);
            }
    }
}

// ---------------- final projection: out[8192][10] = act @ wout ----------------
__global__ __launch_bounds__(256)
void out_gemm(const unsigned short* __restrict__ act,  // [8192][512] bf16
              const float* __restrict__ wout,          // [512][10]
              float* __restrict__ out)                 // [8192][10]
{
    __shared__ float sw[NPAD * NOUT];
    const int tid = threadIdx.x;
    for (int i = tid; i < NPAD*NOUT; i += 256) sw[i] = wout[i];
    __syncthreads();

    const int lane = tid & 63;
    const int wv   = tid >> 6;
    const int row  = blockIdx.x * 4 + wv;

    const unsigned short* ap = act + (long)row * NPAD + lane * 8;
    us4 v0 = *(const us4*)(ap);
    us4 v1 = *(const us4*)(ap + 4);

    float p[NOUT];
    #pragma unroll
    for (int o = 0; o < NOUT; ++o) p[o] = 0.f;

    const int nb = lane * 8;
    #pragma unroll
    for (int e = 0; e < 8; ++e) {
        float a = bf2f(e < 4 ? v0[e] : v1[e-4]);
        const float* wr = &sw[(nb + e) * NOUT];
        #pragma unroll
        for (int o = 0; o < NOUT; ++o) p[o] += a * wr[o];
    }
    #pragma unroll
    for (int o = 0; o < NOUT; ++o) {
        float s = p[o];
        for (int d = 32; d > 0; d >>= 1) s += __shfl_down(s, d);
        if (lane == 0) out[(long)row * NOUT + o] = s;
    }
}

extern "C" void kernel_launch(void* const* d_in, const int* in_sizes, int n_in,
                              void* d_out, int out_size, void* d_ws, size_t ws_size,
                              hipStream_t stream)
{
    const float* x        = (const float*)d_in[0];
    const float* pos      = (const float*)d_in[1];
    const float* in_w     = (const float*)d_in[2];
    const float* feats    = (const float*)d_in[3];
    const float* out_w    = (const float*)d_in[4];
    const float* biases   = (const float*)d_in[5];
    float* out = (float*)d_out;

    char* ws = (char*)d_ws;
    unsigned short* iw_bf  = (unsigned short*)(ws);                  //  3,145,728 B
    unsigned short* connw  = (unsigned short*)(ws + 3145728);        //    524,288 B
    unsigned short* act_a  = (unsigned short*)(ws + 3670016);        //  8,388,608 B
    unsigned short* act_b  = (unsigned short*)(ws + 12058624);       //  8,388,608 B
    float* feat_norm = (float*)(ws + 20447232);                      //    131,072 B
    float* pos_c     = (float*)(ws + 20578304);                      //      8,192 B
    float* inw       = (float*)(ws + 20586496);                      //      2,048 B
    float* biasp     = (float*)(ws + 20588544);                      //      2,048 B
    float* wout      = (float*)(ws + 20590592);                      //     20,480 B

    prep1<<<1, 512, 0, stream>>>(pos, feats, out_w, biases, feat_norm, pos_c, inw, biasp, wout);
    prep2<<<512, 128, 0, stream>>>(pos_c, feat_norm, connw);
    cast_pad<<<512, 256, 0, stream>>>(in_w, iw_bf, 393216L, 384000L);

    gemm_main<0><<<256, 512, 0, stream>>>(x, nullptr, iw_bf, act_a, nullptr, inw, biasp, K_IN);
    gemm_main<1><<<256, 512, 0, stream>>>(nullptr, act_a, connw, act_b, act_a, nullptr, nullptr, NPAD);
    gemm_main<1><<<256, 512, 0, stream>>>(nullptr, act_b, connw, act_a, act_b, nullptr, nullptr, NPAD);
    gemm_main<1><<<256, 512, 0, stream>>>(nullptr, act_a, connw, act_b, act_a, nullptr, nullptr, NPAD);

    out_gemm<<<NBATCH/4, 256, 0, stream>>>(act_b, wout, out);
}

// Round 7
// 132.826 us; speedup vs baseline: 1.0340x; 1.0340x over previous
//
#include <hip/hip_runtime.h>
#include <stdint.h>

#define N_REAL 500
#define NPAD   512
#define K_IN   3072
#define NBATCH 8192
#define NOUT   10
#define RADIUS 20.0f
#define VOLF   100.0f

typedef __attribute__((ext_vector_type(8))) __bf16 bf16x8;
typedef __attribute__((ext_vector_type(4))) float  f32x4;
typedef __attribute__((ext_vector_type(4))) unsigned short us4;

__device__ __forceinline__ unsigned short f2bf(float f) {
    unsigned int u = __float_as_uint(f);
    u += 0x7FFFu + ((u >> 16) & 1u);           // round-to-nearest-even
    return (unsigned short)(u >> 16);
}
__device__ __forceinline__ float bf2f(unsigned short h) {
    return __uint_as_float(((unsigned int)h) << 16);
}
// 8x f32 -> bf16x8 via HW packed cvt (RNE; bitwise == f2bf)
__device__ __forceinline__ bf16x8 cvt8(float4 lo, float4 hi) {
    union { unsigned int u[4]; bf16x8 v; } x;
    asm("v_cvt_pk_bf16_f32 %0, %1, %2" : "=v"(x.u[0]) : "v"(lo.x), "v"(lo.y));
    asm("v_cvt_pk_bf16_f32 %0, %1, %2" : "=v"(x.u[1]) : "v"(lo.z), "v"(lo.w));
    asm("v_cvt_pk_bf16_f32 %0, %1, %2" : "=v"(x.u[2]) : "v"(hi.x), "v"(hi.y));
    asm("v_cvt_pk_bf16_f32 %0, %1, %2" : "=v"(x.u[3]) : "v"(hi.z), "v"(hi.w));
    return x.v;
}

#define GLOBAL_AS __attribute__((address_space(1)))
#define LDS_AS    __attribute__((address_space(3)))
__device__ __forceinline__ void glds16(const void* g, void* l) {
    __builtin_amdgcn_global_load_lds((const GLOBAL_AS void*)g, (LDS_AS void*)l, 16, 0, 0);
}

// ---------------- prep1 ----------------
__global__ void prep1(const float* __restrict__ positions,
                      const float* __restrict__ features,
                      const float* __restrict__ out_w,
                      const float* __restrict__ biases,
                      float* __restrict__ feat_norm,   // [512][64]
                      float* __restrict__ pos_c,       // [512][4]
                      float* __restrict__ inw,         // [512]
                      float* __restrict__ biasp,       // [512]
                      float* __restrict__ wout)        // [512][10]
{
    int n = threadIdx.x;  // 512 threads, 1 block
    float e_in = 0.f, e_out = 0.f;
    float px = 0.f, py = 0.f, pz = 0.f;
    if (n < N_REAL) {
        px = fminf(fmaxf(positions[n*3+0], 0.1f), VOLF - 0.1f);
        py = fminf(fmaxf(positions[n*3+1], 0.1f), VOLF - 0.1f);
        pz = fminf(fmaxf(positions[n*3+2], 0.1f), VOLF - 0.1f);
        float xn = px / VOLF;
        e_in  = expf(-2.f * xn);
        e_out = expf(2.f * (xn - 1.f));
        float ss = 0.f;
        for (int f = 0; f < 64; ++f) { float v = features[n*64+f]; ss += v*v; }
        float nm = fmaxf(sqrtf(ss), 1e-6f);
        for (int f = 0; f < 64; ++f) feat_norm[n*64+f] = features[n*64+f] / nm;
    } else {
        for (int f = 0; f < 64; ++f) feat_norm[n*64+f] = 0.f;
    }
    pos_c[n*4+0] = px; pos_c[n*4+1] = py; pos_c[n*4+2] = pz; pos_c[n*4+3] = 0.f;

    __shared__ float s_in[512], s_out[512];
    s_in[n] = e_in; s_out[n] = e_out;
    __syncthreads();
    for (int s = 256; s > 0; s >>= 1) {
        if (n < s) { s_in[n] += s_in[n+s]; s_out[n] += s_out[n+s]; }
        __syncthreads();
    }
    float sum_in  = s_in[0]  + 1e-6f;
    float sum_out = s_out[0] + 1e-6f;

    inw[n]   = (n < N_REAL) ? (e_in / sum_in) : 0.f;
    biasp[n] = (n < N_REAL) ? biases[n] : 0.f;
    float wo = (n < N_REAL) ? (e_out / sum_out) : 0.f;
    for (int o = 0; o < NOUT; ++o)
        wout[n*NOUT + o] = (n < N_REAL) ? out_w[n*NOUT + o] * wo : 0.f;
}

// ---------------- prep2 ----------------
__global__ void prep2(const float* __restrict__ pos_c,
                      const float* __restrict__ feat_norm,
                      unsigned short* __restrict__ conn_w)   // [512][512] bf16
{
    int i = blockIdx.x;   // 512
    int t = threadIdx.x;  // 128
    __shared__ float fi[64];
    __shared__ float spos[4];
    __shared__ float red[128];
    if (t < 64) fi[t] = feat_norm[i*64 + t];
    if (t < 4)  spos[t] = pos_c[i*4 + t];
    __syncthreads();

    float w[4];
    float part = 0.f;
    for (int jj = 0; jj < 4; ++jj) {
        int j = t + jj*128;
        float val = 0.f;
        if (i < N_REAL && j < N_REAL) {
            float dx = spos[0] - pos_c[j*4+0];
            float dy = spos[1] - pos_c[j*4+1];
            float dz = spos[2] - pos_c[j*4+2];
            float sq = dx*dx + dy*dy + dz*dz;
            if (sq > 0.f) {
                float dist = sqrtf(sq);
                if (dist < RADIUS) {
                    float att = expf(-dist / RADIUS);
                    float sim = 0.f;
                    const float4* fj = (const float4*)(feat_norm + j*64);
                    const float4* fi4 = (const float4*)fi;
                    #pragma unroll
                    for (int f = 0; f < 16; ++f) {
                        float4 a = fi4[f]; float4 b = fj[f];
                        sim += a.x*b.x + a.y*b.y + a.z*b.z + a.w*b.w;
                    }
                    sim = fminf(fmaxf(sim, -1.f), 1.f);
                    val = att * (0.5f + 0.5f*sim);
                }
            }
        }
        w[jj] = val; part += val;
    }
    red[t] = part;
    __syncthreads();
    for (int s = 64; s > 0; s >>= 1) {
        if (t < s) red[t] += red[t+s];
        __syncthreads();
    }
    float inv = 1.f / (red[0] + 1e-6f);
    for (int jj = 0; jj < 4; ++jj)
        conn_w[(long)i*NPAD + t + jj*128] = f2bf(w[jj] * inv);
}

// ---------------- cast/pad f32 -> bf16 ----------------
__global__ void cast_pad(const float* __restrict__ src, unsigned short* __restrict__ dst,
                         long total_q, long src_q)
{
    long i = (long)blockIdx.x * blockDim.x + threadIdx.x;
    long stride = (long)gridDim.x * blockDim.x;
    for (; i < total_q; i += stride) {
        us4 o;
        if (i < src_q) {
            float4 v = ((const float4*)src)[i];
            o[0] = f2bf(v.x); o[1] = f2bf(v.y); o[2] = f2bf(v.z); o[3] = f2bf(v.w);
        } else {
            o[0] = 0; o[1] = 0; o[2] = 0; o[3] = 0;
        }
        ((us4*)dst)[i] = o;
    }
}

// Block map for 256 blocks = 128 m-panels x 2 n-halves.
__device__ __forceinline__ void block_map(int b, int& m0, int& n0) {
    int xcd = b & 7, loc = b >> 3;          // loc 0..31
    m0 = (xcd*16 + (loc >> 1)) * 64;
    n0 = (loc & 1) * 256;
}

// ============ unified GEMM: BM=64, BN=256, BK=64, 512 thr (8 waves 2m x 4n) ============
// Depth-2, 3-buffer, ALL-glds16 pipeline: tile t+2 issued at step t, vmcnt keeps
// tiles t+1,t+2 in flight across both barriers -> memory pipe never drains.
// MODE 0: A = X staged as F32 in LDS (cvt to bf16 after ds_read); C = acc*inw+bias
// MODE 1: A = act bf16; C = min(relu(actOld + 0.5*acc), 50)
template<int MODE>
__global__ __launch_bounds__(512)
void gemm_main(const float* __restrict__ Xf,           // MODE0: [8192][3072] f32
               const unsigned short* __restrict__ Abf, // MODE1: [8192][512] bf16
               const unsigned short* __restrict__ B,   // [512][K] bf16
               unsigned short* __restrict__ Cbf,       // [8192][512] bf16
               const unsigned short* __restrict__ actOld,
               const float* __restrict__ inw,
               const float* __restrict__ biasp,
               int K)
{
    constexpr int ABUF = (MODE == 0) ? 16384 : 8192;   // A tile bytes (f32 / bf16)
    constexpr int BBUF = 32768;                        // B tile: 256 x 64 bf16
    __shared__ __align__(16) char lds[3*ABUF + 3*BBUF]; // 144 KB / 120 KB

    const int tid  = threadIdx.x;
    const int lane = tid & 63;
    const int wave = tid >> 6;
    int m0, n0; block_map(blockIdx.x, m0, n0);
    const int wm = (wave >> 2) * 32;          // 2 m-waves
    const int wn = (wave & 3) * 64;           // 4 n-waves

    f32x4 acc[2][4];
    #pragma unroll
    for (int i = 0; i < 2; ++i)
        #pragma unroll
        for (int j = 0; j < 4; ++j)
            acc[i][j] = (f32x4){0.f,0.f,0.f,0.f};

    // ---- staging descriptors (all glds16, pre-swizzled global sources) ----
    // B: 32 KB/tile -> 4 glds16/thread; 128 B rows, swz ((row&7)<<4)
    const char* gB[4]; int lBo[4];
    #pragma unroll
    for (int s = 0; s < 4; ++s) {
        int o = tid*16 + s*8192;
        int row = o >> 7, d = o & 127;
        gB[s] = (const char*)B + (long)(n0 + row) * (K*2) + (d ^ ((row & 7) << 4));
        lBo[s] = o;
    }
    // A MODE0: f32 tile 64x64 = 16 KB -> 2 glds16/thread; 256 B rows,
    //          16B-slot swz (slot ^ (row&15))  [2-way bank alias = free]
    // A MODE1: bf16 tile 64x64 = 8 KB -> 1 glds16/thread; 128 B rows, swz ((row&7)<<4)
    const char* gA[2]; int lAo[2];
    if (MODE == 0) {
        #pragma unroll
        for (int s = 0; s < 2; ++s) {
            int o = tid*16 + s*8192;
            int row = o >> 8, slot = (o >> 4) & 15;
            gA[s] = (const char*)Xf + (long)(m0 + row) * (K*4) + ((slot ^ (row & 15)) << 4);
            lAo[s] = o;
        }
    } else {
        int o = tid*16;
        int row = o >> 7, d = o & 127;
        gA[0] = (const char*)Abf + (long)(m0 + row) * (K*2) + (d ^ ((row & 7) << 4));
        lAo[0] = o;
        gA[1] = nullptr; lAo[1] = 0;
    }

    const int NT = K >> 6;   // 48 or 8

#define ISSUE_TILE(p)                                                          \
    do {                                                                       \
        if (MODE == 0) {                                                       \
            glds16(gA[0], lds + (p)*ABUF + lAo[0]); gA[0] += 256;              \
            glds16(gA[1], lds + (p)*ABUF + lAo[1]); gA[1] += 256;              \
        } else {                                                               \
            glds16(gA[0], lds + (p)*ABUF + lAo[0]); gA[0] += 128;              \
        }                                                                      \
        glds16(gB[0], lds + 3*ABUF + (p)*BBUF + lBo[0]); gB[0] += 128;         \
        glds16(gB[1], lds + 3*ABUF + (p)*BBUF + lBo[1]); gB[1] += 128;         \
        glds16(gB[2], lds + 3*ABUF + (p)*BBUF + lBo[2]); gB[2] += 128;         \
        glds16(gB[3], lds + 3*ABUF + (p)*BBUF + lBo[3]); gB[3] += 128;         \
    } while (0)

    // prologue: tiles 0 and 1 in flight
    ISSUE_TILE(0);
    ISSUE_TILE(1);

    int cur = 0;
    for (int t = 0; t < NT; ++t) {
        int p2 = cur + 2; if (p2 >= 3) p2 -= 3;
        if (t + 2 < NT) {
            ISSUE_TILE(p2);
            // outstanding: t(6|5), t+1(6|5), t+2(6|5) -> drain tile t only
            if (MODE == 0) asm volatile("s_waitcnt vmcnt(12)" ::: "memory");
            else           asm volatile("s_waitcnt vmcnt(10)" ::: "memory");
        } else if (t + 1 < NT) {
            if (MODE == 0) asm volatile("s_waitcnt vmcnt(6)" ::: "memory");
            else           asm volatile("s_waitcnt vmcnt(5)" ::: "memory");
        } else {
            asm volatile("s_waitcnt vmcnt(0)" ::: "memory");
        }
        __builtin_amdgcn_s_barrier();   // tile t resident for all waves

        const char* Ab = lds + cur*ABUF;
        const char* Bb = lds + 3*ABUF + cur*BBUF;
        #pragma unroll
        for (int kk = 0; kk < 2; ++kk) {
            bf16x8 afr[2], bfr[4];
            if (MODE == 0) {
                #pragma unroll
                for (int i = 0; i < 2; ++i) {
                    int r = wm + i*16 + (lane & 15);
                    int s0 = kk*8 + (lane >> 4)*2;
                    float4 lo = *(const float4*)(Ab + r*256 + (((s0    ) ^ (r & 15)) << 4));
                    float4 hi = *(const float4*)(Ab + r*256 + (((s0 + 1) ^ (r & 15)) << 4));
                    afr[i] = cvt8(lo, hi);
                }
            } else {
                #pragma unroll
                for (int i = 0; i < 2; ++i) {
                    int r = wm + i*16 + (lane & 15);
                    afr[i] = *(const bf16x8*)(Ab + r*128 + ((kk*64 + (lane >> 4)*16) ^ ((r & 7) << 4)));
                }
            }
            #pragma unroll
            for (int j = 0; j < 4; ++j) {
                int r = wn + j*16 + (lane & 15);
                bfr[j] = *(const bf16x8*)(Bb + r*128 + ((kk*64 + (lane >> 4)*16) ^ ((r & 7) << 4)));
            }
            #pragma unroll
            for (int i = 0; i < 2; ++i)
                #pragma unroll
                for (int j = 0; j < 4; ++j)
                    acc[i][j] = __builtin_amdgcn_mfma_f32_16x16x32_bf16(afr[i], bfr[j], acc[i][j], 0, 0, 0);
        }
        __builtin_amdgcn_s_barrier();   // reads done before buffer reuse
        cur = (cur == 2) ? 0 : cur + 1;
    }
#undef ISSUE_TILE

    // ---- epilogue ----
    const int mbase = m0 + wm + (lane >> 4) * 4;
    const int nbase = n0 + wn + (lane & 15);
    #pragma unroll
    for (int j = 0; j < 4; ++j) {
        const int n = nbase + j*16;
        float win = 0.f, bia = 0.f;
        if (MODE == 0) { win = inw[n]; bia = biasp[n]; }
        #pragma unroll
        for (int i = 0; i < 2; ++i)
            #pragma unroll
            for (int r = 0; r < 4; ++r) {
                const long m = mbase + i*16 + r;
                float vv;
                if (MODE == 0) {
                    vv = acc[i][j][r] * win + bia;
                } else {
                    float old = bf2f(actOld[m*NPAD + n]);
                    vv = fminf(fmaxf(old + 0.5f * acc[i][j][r], 0.f), 50.f);
                }
                Cbf[m*NPAD + n] = f2bf(vv);
            }
    }
}

// ---------------- final projection: out[8192][10] = act @ wout ----------------
__global__ __launch_bounds__(256)
void out_gemm(const unsigned short* __restrict__ act,  // [8192][512] bf16
              const float* __restrict__ wout,          // [512][10]
              float* __restrict__ out)                 // [8192][10]
{
    __shared__ float sw[NPAD * NOUT];
    const int tid = threadIdx.x;
    for (int i = tid; i < NPAD*NOUT; i += 256) sw[i] = wout[i];
    __syncthreads();

    const int lane = tid & 63;
    const int wv   = tid >> 6;
    const int row  = blockIdx.x * 4 + wv;

    const unsigned short* ap = act + (long)row * NPAD + lane * 8;
    us4 v0 = *(const us4*)(ap);
    us4 v1 = *(const us4*)(ap + 4);

    float p[NOUT];
    #pragma unroll
    for (int o = 0; o < NOUT; ++o) p[o] = 0.f;

    const int nb = lane * 8;
    #pragma unroll
    for (int e = 0; e < 8; ++e) {
        float a = bf2f(e < 4 ? v0[e] : v1[e-4]);
        const float* wr = &sw[(nb + e) * NOUT];
        #pragma unroll
        for (int o = 0; o < NOUT; ++o) p[o] += a * wr[o];
    }
    #pragma unroll
    for (int o = 0; o < NOUT; ++o) {
        float s = p[o];
        for (int d = 32; d > 0; d >>= 1) s += __shfl_down(s, d);
        if (lane == 0) out[(long)row * NOUT + o] = s;
    }
}

extern "C" void kernel_launch(void* const* d_in, const int* in_sizes, int n_in,
                              void* d_out, int out_size, void* d_ws, size_t ws_size,
                              hipStream_t stream)
{
    const float* x        = (const float*)d_in[0];
    const float* pos      = (const float*)d_in[1];
    const float* in_w     = (const float*)d_in[2];
    const float* feats    = (const float*)d_in[3];
    const float* out_w    = (const float*)d_in[4];
    const float* biases   = (const float*)d_in[5];
    float* out = (float*)d_out;

    char* ws = (char*)d_ws;
    unsigned short* iw_bf  = (unsigned short*)(ws);                  //  3,145,728 B
    unsigned short* connw  = (unsigned short*)(ws + 3145728);        //    524,288 B
    unsigned short* act_a  = (unsigned short*)(ws + 3670016);        //  8,388,608 B
    unsigned short* act_b  = (unsigned short*)(ws + 12058624);       //  8,388,608 B
    float* feat_norm = (float*)(ws + 20447232);                      //    131,072 B
    float* pos_c     = (float*)(ws + 20578304);                      //      8,192 B
    float* inw       = (float*)(ws + 20586496);                      //      2,048 B
    float* biasp     = (float*)(ws + 20588544);                      //      2,048 B
    float* wout      = (float*)(ws + 20590592);                      //     20,480 B

    prep1<<<1, 512, 0, stream>>>(pos, feats, out_w, biases, feat_norm, pos_c, inw, biasp, wout);
    prep2<<<512, 128, 0, stream>>>(pos_c, feat_norm, connw);
    cast_pad<<<512, 256, 0, stream>>>(in_w, iw_bf, 393216L, 384000L);

    gemm_main<0><<<256, 512, 0, stream>>>(x, nullptr, iw_bf, act_a, nullptr, inw, biasp, K_IN);
    gemm_main<1><<<256, 512, 0, stream>>>(nullptr, act_a, connw, act_b, act_a, nullptr, nullptr, NPAD);
    gemm_main<1><<<256, 512, 0, stream>>>(nullptr, act_b, connw, act_a, act_b, nullptr, nullptr, NPAD);
    gemm_main<1><<<256, 512, 0, stream>>>(nullptr, act_a, connw, act_b, act_a, nullptr, nullptr, NPAD);

    out_gemm<<<NBATCH/4, 256, 0, stream>>>(act_b, wout, out);
}

// Round 8
// 115.593 us; speedup vs baseline: 1.1881x; 1.1491x over previous
//
#include <hip/hip_runtime.h>
#include <stdint.h>

#define N_REAL 500
#define NPAD   512
#define K_IN   3072
#define NBATCH 8192
#define NOUT   10
#define RADIUS 20.0f
#define VOLF   100.0f

typedef __attribute__((ext_vector_type(8))) __bf16 bf16x8;
typedef __attribute__((ext_vector_type(4))) float  f32x4;
typedef __attribute__((ext_vector_type(4))) unsigned short us4;

__device__ __forceinline__ unsigned short f2bf(float f) {
    unsigned int u = __float_as_uint(f);
    u += 0x7FFFu + ((u >> 16) & 1u);           // round-to-nearest-even
    return (unsigned short)(u >> 16);
}
__device__ __forceinline__ float bf2f(unsigned short h) {
    return __uint_as_float(((unsigned int)h) << 16);
}
// HW packed f32->bf16 (RNE), 2 insts per float4
__device__ __forceinline__ uint2 cvt_pk4(float4 v) {
    uint2 r;
    asm("v_cvt_pk_bf16_f32 %0, %1, %2" : "=v"(r.x) : "v"(v.x), "v"(v.y));
    asm("v_cvt_pk_bf16_f32 %0, %1, %2" : "=v"(r.y) : "v"(v.z), "v"(v.w));
    return r;
}

#define GLOBAL_AS __attribute__((address_space(1)))
#define LDS_AS    __attribute__((address_space(3)))
__device__ __forceinline__ void glds16(const void* g, void* l) {
    __builtin_amdgcn_global_load_lds((const GLOBAL_AS void*)g, (LDS_AS void*)l, 16, 0, 0);
}

// ---------------- prep1 ----------------
__global__ void prep1(const float* __restrict__ positions,
                      const float* __restrict__ features,
                      const float* __restrict__ out_w,
                      const float* __restrict__ biases,
                      float* __restrict__ feat_norm,   // [512][64]
                      float* __restrict__ pos_c,       // [512][4]
                      float* __restrict__ inw,         // [512]
                      float* __restrict__ biasp,       // [512]
                      float* __restrict__ wout)        // [512][10]
{
    int n = threadIdx.x;  // 512 threads, 1 block
    float e_in = 0.f, e_out = 0.f;
    float px = 0.f, py = 0.f, pz = 0.f;
    if (n < N_REAL) {
        px = fminf(fmaxf(positions[n*3+0], 0.1f), VOLF - 0.1f);
        py = fminf(fmaxf(positions[n*3+1], 0.1f), VOLF - 0.1f);
        pz = fminf(fmaxf(positions[n*3+2], 0.1f), VOLF - 0.1f);
        float xn = px / VOLF;
        e_in  = expf(-2.f * xn);
        e_out = expf(2.f * (xn - 1.f));
        float ss = 0.f;
        for (int f = 0; f < 64; ++f) { float v = features[n*64+f]; ss += v*v; }
        float nm = fmaxf(sqrtf(ss), 1e-6f);
        for (int f = 0; f < 64; ++f) feat_norm[n*64+f] = features[n*64+f] / nm;
    } else {
        for (int f = 0; f < 64; ++f) feat_norm[n*64+f] = 0.f;
    }
    pos_c[n*4+0] = px; pos_c[n*4+1] = py; pos_c[n*4+2] = pz; pos_c[n*4+3] = 0.f;

    __shared__ float s_in[512], s_out[512];
    s_in[n] = e_in; s_out[n] = e_out;
    __syncthreads();
    for (int s = 256; s > 0; s >>= 1) {
        if (n < s) { s_in[n] += s_in[n+s]; s_out[n] += s_out[n+s]; }
        __syncthreads();
    }
    float sum_in  = s_in[0]  + 1e-6f;
    float sum_out = s_out[0] + 1e-6f;

    inw[n]   = (n < N_REAL) ? (e_in / sum_in) : 0.f;
    biasp[n] = (n < N_REAL) ? biases[n] : 0.f;
    float wo = (n < N_REAL) ? (e_out / sum_out) : 0.f;
    for (int o = 0; o < NOUT; ++o)
        wout[n*NOUT + o] = (n < N_REAL) ? out_w[n*NOUT + o] * wo : 0.f;
}

// ---------------- prep2 ----------------
__global__ void prep2(const float* __restrict__ pos_c,
                      const float* __restrict__ feat_norm,
                      unsigned short* __restrict__ conn_w)   // [512][512] bf16
{
    int i = blockIdx.x;   // 512
    int t = threadIdx.x;  // 128
    __shared__ float fi[64];
    __shared__ float spos[4];
    __shared__ float red[128];
    if (t < 64) fi[t] = feat_norm[i*64 + t];
    if (t < 4)  spos[t] = pos_c[i*4 + t];
    __syncthreads();

    float w[4];
    float part = 0.f;
    for (int jj = 0; jj < 4; ++jj) {
        int j = t + jj*128;
        float val = 0.f;
        if (i < N_REAL && j < N_REAL) {
            float dx = spos[0] - pos_c[j*4+0];
            float dy = spos[1] - pos_c[j*4+1];
            float dz = spos[2] - pos_c[j*4+2];
            float sq = dx*dx + dy*dy + dz*dz;
            if (sq > 0.f) {
                float dist = sqrtf(sq);
                if (dist < RADIUS) {
                    float att = expf(-dist / RADIUS);
                    float sim = 0.f;
                    const float4* fj = (const float4*)(feat_norm + j*64);
                    const float4* fi4 = (const float4*)fi;
                    #pragma unroll
                    for (int f = 0; f < 16; ++f) {
                        float4 a = fi4[f]; float4 b = fj[f];
                        sim += a.x*b.x + a.y*b.y + a.z*b.z + a.w*b.w;
                    }
                    sim = fminf(fmaxf(sim, -1.f), 1.f);
                    val = att * (0.5f + 0.5f*sim);
                }
            }
        }
        w[jj] = val; part += val;
    }
    red[t] = part;
    __syncthreads();
    for (int s = 64; s > 0; s >>= 1) {
        if (t < s) red[t] += red[t+s];
        __syncthreads();
    }
    float inv = 1.f / (red[0] + 1e-6f);
    for (int jj = 0; jj < 4; ++jj)
        conn_w[(long)i*NPAD + t + jj*128] = f2bf(w[jj] * inv);
}

// ---------------- cast/pad f32 -> bf16 ----------------
__global__ void cast_pad(const float* __restrict__ src, unsigned short* __restrict__ dst,
                         long total_q, long src_q)
{
    long i = (long)blockIdx.x * blockDim.x + threadIdx.x;
    long stride = (long)gridDim.x * blockDim.x;
    for (; i < total_q; i += stride) {
        us4 o;
        if (i < src_q) {
            float4 v = ((const float4*)src)[i];
            o[0] = f2bf(v.x); o[1] = f2bf(v.y); o[2] = f2bf(v.z); o[3] = f2bf(v.w);
        } else {
            o[0] = 0; o[1] = 0; o[2] = 0; o[3] = 0;
        }
        ((us4*)dst)[i] = o;
    }
}

// Block map for 512 blocks = 128 m-panels x 4 n-quarters.
// XCD owns 16 m-panels; the 4 n-blocks of an m-panel are adjacent on the same
// XCD so the A-panel re-reads hit that XCD's L2.
__device__ __forceinline__ void block_map(int b, int& m0, int& n0) {
    int xcd = b & 7, loc = b >> 3;          // loc 0..63
    m0 = (xcd*16 + (loc >> 2)) * 64;
    n0 = (loc & 3) * 128;
}

// ============ GEMM: BM=64, BN=128, BK=64, 256 thr (4 waves 2m x 2n) ============
// 3-buffer ring, depth-2 counted vmcnt, 2 blocks/CU (72 KB LDS).
// MODE 0: A = X f32, reg-staged cast (issue-early / ds_write-late, T14);
//         per tile: 4 f32x4 loads + 4 B-glds16.  C = acc*inw + bias.
// MODE 1: A,B via glds16 (2+4 per tile).  C = min(relu(actOld + 0.5*acc), 50).
template<int MODE>
__global__ __launch_bounds__(256, 4)
void gemm_pipe(const float* __restrict__ Xf,
               const unsigned short* __restrict__ Abf,
               const unsigned short* __restrict__ B,   // [512][K] bf16
               unsigned short* __restrict__ Cbf,       // [8192][512] bf16
               const unsigned short* __restrict__ actOld,
               const float* __restrict__ inw,
               const float* __restrict__ biasp,
               int K)
{
    constexpr int ABUF = 8192;    // 64 x 64 bf16
    constexpr int BBUF = 16384;   // 128 x 64 bf16
    __shared__ __align__(16) char lds[3*(ABUF+BBUF)];  // 72 KB
    char* const Abase = lds;
    char* const Bbase = lds + 3*ABUF;

    const int tid  = threadIdx.x;
    const int lane = tid & 63;
    const int wave = tid >> 6;
    int m0, n0; block_map(blockIdx.x, m0, n0);
    const int wm = (wave >> 1) * 32;          // 2 m-waves
    const int wn = (wave & 1) * 64;           // 2 n-waves

    f32x4 acc[2][4];
    #pragma unroll
    for (int i = 0; i < 2; ++i)
        #pragma unroll
        for (int j = 0; j < 4; ++j)
            acc[i][j] = (f32x4){0.f,0.f,0.f,0.f};

    // ---- staging descriptors ----
    // B: 16 KB/tile -> 4 glds16/thread; 128 B rows, swz ((row&7)<<4)
    const char* gB[4]; int lBo[4];
    #pragma unroll
    for (int s = 0; s < 4; ++s) {
        int o = tid*16 + s*4096;
        int row = o >> 7, d = o & 127;
        gB[s] = (const char*)B + (long)(n0 + row) * (K*2) + (d ^ ((row & 7) << 4));
        lBo[s] = o;
    }
    // A MODE0: 64 rows x 16 float4 -> 4 f4/thread, reg-stage + cvt + ds_write_b64
    const float4* gA[4]; int lAo[4];
    // A MODE1: 8 KB/tile -> 2 glds16/thread
    const char* gA1[2]; int lAo1[2];
    if (MODE == 0) {
        #pragma unroll
        for (int s = 0; s < 4; ++s) {
            int f = tid + s*256;
            int row = f >> 4, c4 = f & 15;
            gA[s] = (const float4*)(Xf + (long)(m0 + row) * K) + c4;
            lAo[s] = row*128 + ((c4*8) ^ ((row & 7) << 4));
        }
    } else {
        #pragma unroll
        for (int s = 0; s < 2; ++s) {
            int o = tid*16 + s*4096;
            int row = o >> 7, d = o & 127;
            gA1[s] = (const char*)Abf + (long)(m0 + row) * (K*2) + (d ^ ((row & 7) << 4));
            lAo1[s] = o;
        }
    }

    const int NT = K >> 6;   // 48 or 8
    float4 v[4];

    // ---- prologue ----
    if (MODE == 0) {
        // tile 0: f4 loads, then B glds
        #pragma unroll
        for (int s = 0; s < 4; ++s) { v[s] = gA[s][0]; gA[s] += 16; }
        __builtin_amdgcn_sched_barrier(0);
        #pragma unroll
        for (int s = 0; s < 4; ++s) { glds16(gB[s], Bbase + 0*BBUF + lBo[s]); gB[s] += 128; }
        // tile 1
        float4 w4[4];
        #pragma unroll
        for (int s = 0; s < 4; ++s) { w4[s] = gA[s][0]; gA[s] += 16; }
        __builtin_amdgcn_sched_barrier(0);
        #pragma unroll
        for (int s = 0; s < 4; ++s) { glds16(gB[s], Bbase + 1*BBUF + lBo[s]); gB[s] += 128; }
        // write A(0) then A(1) (compiler adds the needed vmcnt for v/w4 uses)
        asm volatile("s_waitcnt vmcnt(12)" ::: "memory");   // f4(0) done
        #pragma unroll
        for (int s = 0; s < 4; ++s)
            *(uint2*)(Abase + 0*ABUF + lAo[s]) = cvt_pk4(v[s]);
        asm volatile("s_waitcnt vmcnt(4)" ::: "memory");    // f4(1) done (B(0) too)
        #pragma unroll
        for (int s = 0; s < 4; ++s)
            *(uint2*)(Abase + 1*ABUF + lAo[s]) = cvt_pk4(w4[s]);
        asm volatile("s_waitcnt lgkmcnt(0)" ::: "memory");
    } else {
        #pragma unroll
        for (int s = 0; s < 2; ++s) { glds16(gA1[s], Abase + 0*ABUF + lAo1[s]); gA1[s] += 128; }
        #pragma unroll
        for (int s = 0; s < 4; ++s) { glds16(gB[s], Bbase + 0*BBUF + lBo[s]); gB[s] += 128; }
        #pragma unroll
        for (int s = 0; s < 2; ++s) { glds16(gA1[s], Abase + 1*ABUF + lAo1[s]); gA1[s] += 128; }
        #pragma unroll
        for (int s = 0; s < 4; ++s) { glds16(gB[s], Bbase + 1*BBUF + lBo[s]); gB[s] += 128; }
    }

    int cur = 0;
    for (int t = 0; t < NT; ++t) {
        int fb = cur + 2; if (fb >= 3) fb -= 3;    // fill buffer (tile t+2)
        const bool more2 = (t + 2 < NT);
        const bool more1 = (t + 1 < NT);

        if (MODE == 0) {
            if (more2) {
                #pragma unroll
                for (int s = 0; s < 4; ++s) { v[s] = gA[s][0]; gA[s] += 16; }
                __builtin_amdgcn_sched_barrier(0);
                #pragma unroll
                for (int s = 0; s < 4; ++s) { glds16(gB[s], Bbase + fb*BBUF + lBo[s]); gB[s] += 128; }
                // queue: [B(t):4, f4(t+2):4, B(t+2):4] -> drain B(t) only
                asm volatile("s_waitcnt vmcnt(8)" ::: "memory");
            } else if (more1) {
                asm volatile("s_waitcnt vmcnt(4)" ::: "memory");
            } else {
                asm volatile("s_waitcnt vmcnt(0)" ::: "memory");
            }
        } else {
            if (more2) {
                #pragma unroll
                for (int s = 0; s < 2; ++s) { glds16(gA1[s], Abase + fb*ABUF + lAo1[s]); gA1[s] += 128; }
                #pragma unroll
                for (int s = 0; s < 4; ++s) { glds16(gB[s], Bbase + fb*BBUF + lBo[s]); gB[s] += 128; }
                // queue: [t:6, t+1:6, t+2:6] -> drain tile t only
                asm volatile("s_waitcnt vmcnt(12)" ::: "memory");
            } else if (more1) {
                asm volatile("s_waitcnt vmcnt(6)" ::: "memory");
            } else {
                asm volatile("s_waitcnt vmcnt(0)" ::: "memory");
            }
        }
        __builtin_amdgcn_s_barrier();   // tile t resident for all waves

        const char* Ab = Abase + cur*ABUF;
        const char* Bb = Bbase + cur*BBUF;
        #pragma unroll
        for (int kk = 0; kk < 2; ++kk) {
            const int cb = kk*64 + (lane >> 4) * 16;
            bf16x8 afr[2], bfr[4];
            #pragma unroll
            for (int i = 0; i < 2; ++i) {
                int r = wm + i*16 + (lane & 15);
                afr[i] = *(const bf16x8*)(Ab + r*128 + (cb ^ ((r & 7) << 4)));
            }
            #pragma unroll
            for (int j = 0; j < 4; ++j) {
                int r = wn + j*16 + (lane & 15);
                bfr[j] = *(const bf16x8*)(Bb + r*128 + (cb ^ ((r & 7) << 4)));
            }
            #pragma unroll
            for (int i = 0; i < 2; ++i)
                #pragma unroll
                for (int j = 0; j < 4; ++j)
                    acc[i][j] = __builtin_amdgcn_mfma_f32_16x16x32_bf16(afr[i], bfr[j], acc[i][j], 0, 0, 0);
        }

        if (MODE == 0 && more2) {
            // write A(t+2) late: f4(t+2) has had the whole MFMA phase in flight
            asm volatile("s_waitcnt vmcnt(4)" ::: "memory");   // f4(t+2) done, B(t+2) stays
            #pragma unroll
            for (int s = 0; s < 4; ++s)
                *(uint2*)(Abase + fb*ABUF + lAo[s]) = cvt_pk4(v[s]);
            asm volatile("s_waitcnt lgkmcnt(0)" ::: "memory");
        }
        __builtin_amdgcn_s_barrier();   // reads of buf cur done before reuse
        cur = (cur == 2) ? 0 : cur + 1;
    }

    // ---- epilogue ----
    const int mbase = m0 + wm + (lane >> 4) * 4;
    const int nbase = n0 + wn + (lane & 15);
    #pragma unroll
    for (int j = 0; j < 4; ++j) {
        const int n = nbase + j*16;
        float win = 0.f, bia = 0.f;
        if (MODE == 0) { win = inw[n]; bia = biasp[n]; }
        #pragma unroll
        for (int i = 0; i < 2; ++i)
            #pragma unroll
            for (int r = 0; r < 4; ++r) {
                const long m = mbase + i*16 + r;
                float vv;
                if (MODE == 0) {
                    vv = acc[i][j][r] * win + bia;
                } else {
                    float old = bf2f(actOld[m*NPAD + n]);
                    vv = fminf(fmaxf(old + 0.5f * acc[i][j][r], 0.f), 50.f);
                }
                Cbf[m*NPAD + n] = f2bf(vv);
            }
    }
}

// ---------------- final projection: out[8192][10] = act @ wout ----------------
__global__ __launch_bounds__(256)
void out_gemm(const unsigned short* __restrict__ act,  // [8192][512] bf16
              const float* __restrict__ wout,          // [512][10]
              float* __restrict__ out)                 // [8192][10]
{
    __shared__ float sw[NPAD * NOUT];
    const int tid = threadIdx.x;
    for (int i = tid; i < NPAD*NOUT; i += 256) sw[i] = wout[i];
    __syncthreads();

    const int lane = tid & 63;
    const int wv   = tid >> 6;
    const int row  = blockIdx.x * 4 + wv;

    const unsigned short* ap = act + (long)row * NPAD + lane * 8;
    us4 v0 = *(const us4*)(ap);
    us4 v1 = *(const us4*)(ap + 4);

    float p[NOUT];
    #pragma unroll
    for (int o = 0; o < NOUT; ++o) p[o] = 0.f;

    const int nb = lane * 8;
    #pragma unroll
    for (int e = 0; e < 8; ++e) {
        float a = bf2f(e < 4 ? v0[e] : v1[e-4]);
        const float* wr = &sw[(nb + e) * NOUT];
        #pragma unroll
        for (int o = 0; o < NOUT; ++o) p[o] += a * wr[o];
    }
    #pragma unroll
    for (int o = 0; o < NOUT; ++o) {
        float s = p[o];
        for (int d = 32; d > 0; d >>= 1) s += __shfl_down(s, d);
        if (lane == 0) out[(long)row * NOUT + o] = s;
    }
}

extern "C" void kernel_launch(void* const* d_in, const int* in_sizes, int n_in,
                              void* d_out, int out_size, void* d_ws, size_t ws_size,
                              hipStream_t stream)
{
    const float* x        = (const float*)d_in[0];
    const float* pos      = (const float*)d_in[1];
    const float* in_w     = (const float*)d_in[2];
    const float* feats    = (const float*)d_in[3];
    const float* out_w    = (const float*)d_in[4];
    const float* biases   = (const float*)d_in[5];
    float* out = (float*)d_out;

    char* ws = (char*)d_ws;
    unsigned short* iw_bf  = (unsigned short*)(ws);                  //  3,145,728 B
    unsigned short* connw  = (unsigned short*)(ws + 3145728);        //    524,288 B
    unsigned short* act_a  = (unsigned short*)(ws + 3670016);        //  8,388,608 B
    unsigned short* act_b  = (unsigned short*)(ws + 12058624);       //  8,388,608 B
    float* feat_norm = (float*)(ws + 20447232);                      //    131,072 B
    float* pos_c     = (float*)(ws + 20578304);                      //      8,192 B
    float* inw       = (float*)(ws + 20586496);                      //      2,048 B
    float* biasp     = (float*)(ws + 20588544);                      //      2,048 B
    float* wout      = (float*)(ws + 20590592);                      //     20,480 B

    prep1<<<1, 512, 0, stream>>>(pos, feats, out_w, biases, feat_norm, pos_c, inw, biasp, wout);
    prep2<<<512, 128, 0, stream>>>(pos_c, feat_norm, connw);
    cast_pad<<<512, 256, 0, stream>>>(in_w, iw_bf, 393216L, 384000L);

    gemm_pipe<0><<<512, 256, 0, stream>>>(x, nullptr, iw_bf, act_a, nullptr, inw, biasp, K_IN);
    gemm_pipe<1><<<512, 256, 0, stream>>>(nullptr, act_a, connw, act_b, act_a, nullptr, nullptr, NPAD);
    gemm_pipe<1><<<512, 256, 0, stream>>>(nullptr, act_b, connw, act_a, act_b, nullptr, nullptr, NPAD);
    gemm_pipe<1><<<512, 256, 0, stream>>>(nullptr, act_a, connw, act_b, act_a, nullptr, nullptr, NPAD);

    out_gemm<<<NBATCH/4, 256, 0, stream>>>(act_b, wout, out);
}